// Round 2
// baseline (351.416 us; speedup 1.0000x reference)
//
#include <hip/hip_runtime.h>
#include <hip/hip_bf16.h>

// SE3StructEncoder: sparse edge-MLP graph network.
// B=2, L=512, H=128, 3 layers. Sparsity (~10% contacts) exploited via
// per-row edge lists; edge GEMM is fp32 register-tiled (MFMA candidate later).

#define Hc 128
#define Lc 512
#define ROWS 1024     // B*L
#define ET 32         // edges per chunk in edge kernel

__device__ __forceinline__ float silu(float x) {
    return x / (1.f + __expf(-x));
}

// ---------------- edge-list build: one wave per (b,i) row ----------------
__global__ __launch_bounds__(64) void build_edges(
    const float* __restrict__ contacts,
    unsigned short* __restrict__ elist, int* __restrict__ ecnt) {
    int r = blockIdx.x;
    int lane = threadIdx.x;
    const float* row = contacts + (size_t)r * Lc;
    int cnt = 0;
    for (int base = 0; base < Lc; base += 64) {
        float v = row[base + lane];
        unsigned long long mask = __ballot(v > 0.f);
        if (v > 0.f) {
            int pos = cnt + __popcll(mask & ((1ull << lane) - 1ull));
            elist[r * Lc + pos] = (unsigned short)(base + lane);
        }
        cnt += __popcll(mask);
    }
    if (lane == 0) ecnt[r] = cnt;
}

// ---------------- input projection: h = nf @ in_w + in_b ----------------
__global__ __launch_bounds__(128) void input_proj(
    const float* __restrict__ nf, const float* __restrict__ w,
    const float* __restrict__ b, float* __restrict__ h) {
    int r0 = blockIdx.x * 4;
    int k = threadIdx.x;
    __shared__ float nfs[4][32];
    nfs[k >> 5][k & 31] = nf[r0 * 32 + k];   // 128 threads load 4x32
    __syncthreads();
    float bias = b[k];
    float acc[4];
#pragma unroll
    for (int rr = 0; rr < 4; rr++) acc[rr] = bias;
#pragma unroll 4
    for (int c = 0; c < 32; c++) {
        float wv = w[c * Hc + k];
#pragma unroll
        for (int rr = 0; rr < 4; rr++) acc[rr] += nfs[rr][c] * wv;
    }
#pragma unroll
    for (int rr = 0; rr < 4; rr++) h[(r0 + rr) * Hc + k] = acc[rr];
}

// ------- hi' = h@w1[:H] + b1 + w1[2H+1] (contact fold), hj = h@w1[H:2H] -------
__global__ __launch_bounds__(128) void hij_kernel(
    const float* __restrict__ h, const float* __restrict__ w1,
    const float* __restrict__ b1,
    float* __restrict__ hi, float* __restrict__ hj) {
    int r0 = blockIdx.x * 4;
    int k = threadIdx.x;
    __shared__ float hs[4][Hc];
#pragma unroll
    for (int rr = 0; rr < 4; rr++) hs[rr][k] = h[(r0 + rr) * Hc + k];
    __syncthreads();
    float bias = b1[k] + w1[(2 * Hc + 1) * Hc + k];
    float a1[4], a2[4];
#pragma unroll
    for (int rr = 0; rr < 4; rr++) { a1[rr] = bias; a2[rr] = 0.f; }
#pragma unroll 4
    for (int c = 0; c < Hc; c++) {
        float wa = w1[c * Hc + k];
        float wb = w1[(Hc + c) * Hc + k];
#pragma unroll
        for (int rr = 0; rr < 4; rr++) {
            a1[rr] += hs[rr][c] * wa;
            a2[rr] += hs[rr][c] * wb;
        }
    }
#pragma unroll
    for (int rr = 0; rr < 4; rr++) {
        hi[(r0 + rr) * Hc + k] = a1[rr];
        hj[(r0 + rr) * Hc + k] = a2[rr];
    }
}

// ---------------- edge kernel: per (b,i) row, sparse edges ----------------
// m_i = sum_{j in edges(i)} silu( silu(pre_ij) @ w2 + b2 )
// pre_ij = hi'[i] + hj[j] + dist(i,j)*w1d       (b1 + contact*w1c folded in hi')
__global__ __launch_bounds__(256) void edge_kernel(
    const float* __restrict__ hi, const float* __restrict__ hj,
    const float* __restrict__ coords,
    const unsigned short* __restrict__ elist, const int* __restrict__ ecnt,
    const float* __restrict__ w1d, const float* __restrict__ w2,
    const float* __restrict__ b2, float* __restrict__ m_out) {
    int r = blockIdx.x;
    int b = r >> 9;
    int i = r & (Lc - 1);
    int t = threadIdx.x;

    __shared__ float hi_s[Hc], w1d_s[Hc];
    __shared__ float sbuf[Hc][ET + 1];   // [c][e], stride 33 -> conflict-free b32
    __shared__ float dL[Lc];
    __shared__ int   jL[Lc];
    __shared__ float red[8][Hc];

    int cnt = ecnt[r];
    if (t < Hc) { hi_s[t] = hi[r * Hc + t]; w1d_s[t] = w1d[t]; }

    float cx = coords[(b * Lc + i) * 3 + 0];
    float cy = coords[(b * Lc + i) * 3 + 1];
    float cz = coords[(b * Lc + i) * 3 + 2];
    for (int e = t; e < cnt; e += 256) {
        int j = elist[r * Lc + e];
        float dx = cx - coords[(b * Lc + j) * 3 + 0];
        float dy = cy - coords[(b * Lc + j) * 3 + 1];
        float dz = cz - coords[(b * Lc + j) * 3 + 2];
        dL[e] = sqrtf(dx * dx + dy * dy + dz * dz);
        jL[e] = j;
    }

    // GEMM mapping: thread -> cols c4..c4+3, edges eg*4..eg*4+3
    int c4 = (t & 31) * 4;
    int eg = t >> 5;                       // 0..7
    float b2r[4];
#pragma unroll
    for (int v = 0; v < 4; v++) b2r[v] = b2[c4 + v];
    float macc[4] = {0.f, 0.f, 0.f, 0.f};
    __syncthreads();

    for (int base = 0; base < cnt; base += ET) {
        int ne = min(ET, cnt - base);
        // fill sbuf: thread t covers one c (=t&127) for 16 edges
        {
            int c = t & 127;
            int eo = t >> 7;
            float hiv = hi_s[c];
            float wdv = w1d_s[c];
#pragma unroll
            for (int u = 0; u < 16; u++) {
                int e = eo * 16 + u;
                float s = 0.f;
                if (e < ne) {
                    int j = jL[base + e];
                    float pre = hiv + hj[((size_t)b * Lc + j) * Hc + c]
                                + dL[base + e] * wdv;
                    s = silu(pre);
                }
                sbuf[c][e] = s;
            }
        }
        __syncthreads();
        // GEMM: t_vals[e][col] = sum_c sbuf[c][e] * w2[c][col]
        float acc[4][4] = {};
#pragma unroll 4
        for (int c = 0; c < Hc; c++) {
            float4 w = *(const float4*)&w2[c * Hc + c4];
#pragma unroll
            for (int u = 0; u < 4; u++) {
                float s = sbuf[c][eg * 4 + u];
                acc[u][0] += s * w.x;
                acc[u][1] += s * w.y;
                acc[u][2] += s * w.z;
                acc[u][3] += s * w.w;
            }
        }
        // second silu + per-edge accumulate
#pragma unroll
        for (int u = 0; u < 4; u++) {
            if (eg * 4 + u < ne) {
#pragma unroll
                for (int v = 0; v < 4; v++) {
                    float tv = acc[u][v] + b2r[v];
                    macc[v] += silu(tv);
                }
            }
        }
        __syncthreads();   // protect sbuf before next fill
    }

    // reduce partial m across 8 edge-groups
#pragma unroll
    for (int v = 0; v < 4; v++) red[eg][c4 + v] = macc[v];
    __syncthreads();
    if (t < Hc) {
        float s = 0.f;
#pragma unroll
        for (int g = 0; g < 8; g++) s += red[g][t];
        m_out[r * Hc + t] = s;
    }
}

// ------------- node update: h += silu(h@w1[:H]+m@w1[H:]+b1)@w2 + b2 -------------
__global__ __launch_bounds__(128) void node_kernel(
    const float* __restrict__ h, const float* __restrict__ m,
    const float* __restrict__ w1, const float* __restrict__ b1,
    const float* __restrict__ w2, const float* __restrict__ b2,
    float* __restrict__ hout) {
    int r0 = blockIdx.x * 4;
    int k = threadIdx.x;
    __shared__ float hs[4][Hc], ms[4][Hc], ss[4][Hc];
#pragma unroll
    for (int rr = 0; rr < 4; rr++) {
        hs[rr][k] = h[(r0 + rr) * Hc + k];
        ms[rr][k] = m[(r0 + rr) * Hc + k];
    }
    __syncthreads();
    float bb = b1[k];
    float acc[4];
#pragma unroll
    for (int rr = 0; rr < 4; rr++) acc[rr] = bb;
#pragma unroll 4
    for (int c = 0; c < Hc; c++) {
        float wa = w1[c * Hc + k];
        float wb = w1[(Hc + c) * Hc + k];
#pragma unroll
        for (int rr = 0; rr < 4; rr++)
            acc[rr] += hs[rr][c] * wa + ms[rr][c] * wb;
    }
#pragma unroll
    for (int rr = 0; rr < 4; rr++) ss[rr][k] = silu(acc[rr]);
    __syncthreads();
    float bb2 = b2[k];
    float a2[4];
#pragma unroll
    for (int rr = 0; rr < 4; rr++) a2[rr] = bb2;
#pragma unroll 4
    for (int c = 0; c < Hc; c++) {
        float wv = w2[c * Hc + k];
#pragma unroll
        for (int rr = 0; rr < 4; rr++) a2[rr] += ss[rr][c] * wv;
    }
#pragma unroll
    for (int rr = 0; rr < 4; rr++)
        hout[(r0 + rr) * Hc + k] = hs[rr][k] + a2[rr];
}

extern "C" void kernel_launch(void* const* d_in, const int* in_sizes, int n_in,
                              void* d_out, int out_size, void* d_ws, size_t ws_size,
                              hipStream_t stream) {
    const float* coords     = (const float*)d_in[0];
    const float* contacts   = (const float*)d_in[1];
    const float* node_feats = (const float*)d_in[2];
    const float* in_w       = (const float*)d_in[3];
    const float* in_b       = (const float*)d_in[4];
    const float* e_w1       = (const float*)d_in[5];   // 3 x 258 x 128
    const float* e_b1       = (const float*)d_in[6];
    const float* e_w2       = (const float*)d_in[7];   // 3 x 128 x 128
    const float* e_b2       = (const float*)d_in[8];
    const float* n_w1       = (const float*)d_in[9];   // 3 x 256 x 128
    const float* n_b1       = (const float*)d_in[10];
    const float* n_w2       = (const float*)d_in[11];  // 3 x 128 x 128
    const float* n_b2       = (const float*)d_in[12];

    float* ws = (float*)d_ws;
    float* h  = ws;                 // 131072 floats
    float* hi = ws + 131072;
    float* hj = ws + 262144;
    float* m  = ws + 393216;
    unsigned short* elist = (unsigned short*)(ws + 524288);  // ROWS*Lc u16 = 1 MiB
    int* ecnt = (int*)(ws + 524288 + 262144);                // after elist

    build_edges<<<ROWS, 64, 0, stream>>>(contacts, elist, ecnt);
    input_proj<<<ROWS / 4, 128, 0, stream>>>(node_feats, in_w, in_b, h);

    for (int l = 0; l < 3; l++) {
        const float* w1  = e_w1 + (size_t)l * 258 * Hc;
        const float* w2e = e_w2 + (size_t)l * Hc * Hc;
        const float* w1n = n_w1 + (size_t)l * 256 * Hc;
        const float* w2n = n_w2 + (size_t)l * Hc * Hc;
        hij_kernel<<<ROWS / 4, 128, 0, stream>>>(h, w1, e_b1 + l * Hc, hi, hj);
        edge_kernel<<<ROWS, 256, 0, stream>>>(hi, hj, coords, elist, ecnt,
                                              w1 + 2 * Hc * Hc, w2e,
                                              e_b2 + l * Hc, m);
        float* hout = (l == 2) ? (float*)d_out : h;
        node_kernel<<<ROWS / 4, 128, 0, stream>>>(h, m, w1n, n_b1 + l * Hc,
                                                  w2n, n_b2 + l * Hc, hout);
    }
}

// Round 4
// 339.921 us; speedup vs baseline: 1.0338x; 1.0338x over previous
//
#include <hip/hip_runtime.h>
#include <hip/hip_bf16.h>

// SE3StructEncoder: sparse edge-MLP graph network. B=2, L=512, H=128, 3 layers.
// Round 3: edge GEMM sbuf -> b128 XOR-swizzled LDS (was ds_read_b32-bound,
// VALUBusy 36% matched LDS-pipe model); hij fused into producers (11->8 dispatches).

#define Hc 128
#define Lc 512
#define ROWS 1024     // B*L
#define ET 32         // edges per chunk in edge kernel

__device__ __forceinline__ float silu(float x) {
    return x / (1.f + __expf(-x));
}

// ---------------- edge-list build: one wave per (b,i) row ----------------
__global__ __launch_bounds__(64) void build_edges(
    const float* __restrict__ contacts,
    unsigned short* __restrict__ elist, int* __restrict__ ecnt) {
    int r = blockIdx.x;
    int lane = threadIdx.x;
    const float* row = contacts + (size_t)r * Lc;
    int cnt = 0;
    for (int base = 0; base < Lc; base += 64) {
        float v = row[base + lane];
        unsigned long long mask = __ballot(v > 0.f);
        if (v > 0.f) {
            int pos = cnt + __popcll(mask & ((1ull << lane) - 1ull));
            elist[r * Lc + pos] = (unsigned short)(base + lane);
        }
        cnt += __popcll(mask);
    }
    if (lane == 0) ecnt[r] = cnt;
}

// ------- input proj + layer-0 hi/hj: 8 rows per block, 256 threads -------
__global__ __launch_bounds__(256) void input_proj_hij(
    const float* __restrict__ nf, const float* __restrict__ in_w,
    const float* __restrict__ in_b,
    const float* __restrict__ w1, const float* __restrict__ b1,
    float* __restrict__ h, float* __restrict__ hi, float* __restrict__ hj) {
    int r0 = blockIdx.x * 8;
    int t = threadIdx.x;
    int k = t & 127, half = t >> 7;
    __shared__ float nfs[8][32];
    __shared__ float hs[8][Hc];
    nfs[t >> 5][t & 31] = nf[r0 * 32 + t];
    __syncthreads();
    float bias = in_b[k];
    float acc[4];
#pragma unroll
    for (int rr = 0; rr < 4; rr++) acc[rr] = bias;
#pragma unroll 4
    for (int c = 0; c < 32; c++) {
        float wv = in_w[c * Hc + k];
#pragma unroll
        for (int rr = 0; rr < 4; rr++) acc[rr] += nfs[half * 4 + rr][c] * wv;
    }
#pragma unroll
    for (int rr = 0; rr < 4; rr++) {
        h[(r0 + half * 4 + rr) * Hc + k] = acc[rr];
        hs[half * 4 + rr][k] = acc[rr];
    }
    __syncthreads();
    // hi' = h@w1[:H] + b1 + w1[257] (contact fold), hj = h@w1[H:2H]
    float bias1 = b1[k] + w1[(2 * Hc + 1) * Hc + k];
    float a1[4], a2[4];
#pragma unroll
    for (int rr = 0; rr < 4; rr++) { a1[rr] = bias1; a2[rr] = 0.f; }
#pragma unroll 4
    for (int c = 0; c < Hc; c++) {
        float wa = w1[c * Hc + k];
        float wb = w1[(Hc + c) * Hc + k];
#pragma unroll
        for (int rr = 0; rr < 4; rr++) {
            a1[rr] += hs[half * 4 + rr][c] * wa;
            a2[rr] += hs[half * 4 + rr][c] * wb;
        }
    }
#pragma unroll
    for (int rr = 0; rr < 4; rr++) {
        hi[(r0 + half * 4 + rr) * Hc + k] = a1[rr];
        hj[(r0 + half * 4 + rr) * Hc + k] = a2[rr];
    }
}

// ---------------- edge kernel: per (b,i) row, sparse edges ----------------
// m_i = sum_{j in edges(i)} silu( silu(pre_ij) @ w2 + b2 )
// pre_ij = hi'[i] + hj[j] + dist(i,j)*w1d     (b1 + contact*w1c folded in hi')
// sbuf layout: [c][16B-block], block index XOR-swizzled by (c&7) so the
// b128 fill-write spreads across all 32 banks; GEMM read is 2-address
// broadcast per wave (free).
__global__ __launch_bounds__(256) void edge_kernel(
    const float* __restrict__ hi, const float* __restrict__ hj,
    const float* __restrict__ coords,
    const unsigned short* __restrict__ elist, const int* __restrict__ ecnt,
    const float* __restrict__ w1d, const float* __restrict__ w2,
    const float* __restrict__ b2, float* __restrict__ m_out) {
    int r = blockIdx.x;
    int b = r >> 9;
    int i = r & (Lc - 1);
    int t = threadIdx.x;

    __shared__ float hi_s[Hc], w1d_s[Hc];
    __shared__ __align__(16) float sbuf[Hc * ET];   // swizzled [c][e]
    __shared__ float dL[Lc];
    __shared__ int   jL[Lc];
    __shared__ float red[8][Hc];

    int cnt = ecnt[r];
    if (t < Hc) { hi_s[t] = hi[r * Hc + t]; w1d_s[t] = w1d[t]; }

    float cx = coords[(b * Lc + i) * 3 + 0];
    float cy = coords[(b * Lc + i) * 3 + 1];
    float cz = coords[(b * Lc + i) * 3 + 2];
    for (int e = t; e < cnt; e += 256) {
        int j = elist[r * Lc + e];
        float dx = cx - coords[(b * Lc + j) * 3 + 0];
        float dy = cy - coords[(b * Lc + j) * 3 + 1];
        float dz = cz - coords[(b * Lc + j) * 3 + 2];
        dL[e] = sqrtf(dx * dx + dy * dy + dz * dz);
        jL[e] = j;
    }

    int c    = t & 127;          // fill: feature index
    int half = t >> 7;           // fill: edge-block half
    int c4   = (t & 31) * 4;     // gemm: output cols
    int eg   = t >> 5;           // gemm: edge group 0..7
    float b2r[4];
#pragma unroll
    for (int v = 0; v < 4; v++) b2r[v] = b2[c4 + v];
    float macc[4] = {0.f, 0.f, 0.f, 0.f};
    const float* hjb = hj + (size_t)b * Lc * Hc + c;
    __syncthreads();

    for (int base = 0; base < cnt; base += ET) {
        int ne = min(ET, cnt - base);
        float hiv = hi_s[c];
        float wdv = w1d_s[c];
        // fill: each thread covers feature c for 4 edge-blocks of 4 edges
#pragma unroll
        for (int p = 0; p < 4; p++) {
            int ebi = half * 4 + p;      // 16B block 0..7
            int e0 = ebi * 4;
            float vals[4];
#pragma unroll
            for (int u = 0; u < 4; u++) {
                int e = e0 + u;
                float s = 0.f;
                if (e < ne) {
                    int j = jL[base + e];
                    float pre = hiv + hjb[j * Hc] + dL[base + e] * wdv;
                    s = silu(pre);
                }
                vals[u] = s;
            }
            int blk = ebi ^ (c & 7);
            *(float4*)&sbuf[c * ET + blk * 4] =
                make_float4(vals[0], vals[1], vals[2], vals[3]);
        }
        __syncthreads();
        // GEMM: acc[e][col] = sum_c sbuf[c][e] * w2[c][col]
        float acc[4][4] = {};
#pragma unroll 4
        for (int cc = 0; cc < Hc; cc++) {
            float4 w = *(const float4*)&w2[cc * Hc + c4];
            float4 s4 = *(const float4*)&sbuf[cc * ET + ((eg ^ (cc & 7)) * 4)];
            acc[0][0] += s4.x * w.x; acc[0][1] += s4.x * w.y;
            acc[0][2] += s4.x * w.z; acc[0][3] += s4.x * w.w;
            acc[1][0] += s4.y * w.x; acc[1][1] += s4.y * w.y;
            acc[1][2] += s4.y * w.z; acc[1][3] += s4.y * w.w;
            acc[2][0] += s4.z * w.x; acc[2][1] += s4.z * w.y;
            acc[2][2] += s4.z * w.z; acc[2][3] += s4.z * w.w;
            acc[3][0] += s4.w * w.x; acc[3][1] += s4.w * w.y;
            acc[3][2] += s4.w * w.z; acc[3][3] += s4.w * w.w;
        }
        // second silu + per-edge accumulate (guard: exclude e >= ne)
#pragma unroll
        for (int u = 0; u < 4; u++) {
            if (eg * 4 + u < ne) {
#pragma unroll
                for (int v = 0; v < 4; v++) {
                    macc[v] += silu(acc[u][v] + b2r[v]);
                }
            }
        }
        __syncthreads();   // protect sbuf before next fill
    }

    // reduce partial m across 8 edge-groups
#pragma unroll
    for (int v = 0; v < 4; v++) red[eg][c4 + v] = macc[v];
    __syncthreads();
    if (t < Hc) {
        float s = 0.f;
#pragma unroll
        for (int g = 0; g < 8; g++) s += red[g][t];
        m_out[r * Hc + t] = s;
    }
}

// ------- node update (+ next layer hi/hj): 8 rows per block, 256 threads -------
// h' = h + silu(h@w1n[:H] + m@w1n[H:] + b1n)@w2n + b2n
// if do_hij: hi = h'@w1e[:H] + b1e + w1e[257];  hj = h'@w1e[H:2H]
__global__ __launch_bounds__(256) void node_hij_kernel(
    const float* __restrict__ h, const float* __restrict__ m,
    const float* __restrict__ w1n, const float* __restrict__ b1n,
    const float* __restrict__ w2n, const float* __restrict__ b2n,
    float* __restrict__ hout, int do_hij,
    const float* __restrict__ w1e, const float* __restrict__ b1e,
    float* __restrict__ hi, float* __restrict__ hj) {
    int r0 = blockIdx.x * 8;
    int t = threadIdx.x;
    int k = t & 127, half = t >> 7;
    __shared__ float hs[8][Hc], ms[8][Hc], ss[8][Hc];
#pragma unroll
    for (int q = 0; q < 4; q++) {
        int idx = q * 256 + t;
        hs[idx >> 7][idx & 127] = h[r0 * Hc + idx];
        ms[idx >> 7][idx & 127] = m[r0 * Hc + idx];
    }
    __syncthreads();
    float acc[4];
    float bb = b1n[k];
#pragma unroll
    for (int rr = 0; rr < 4; rr++) acc[rr] = bb;
#pragma unroll 4
    for (int c = 0; c < Hc; c++) {
        float wa = w1n[c * Hc + k];
        float wb = w1n[(Hc + c) * Hc + k];
#pragma unroll
        for (int rr = 0; rr < 4; rr++)
            acc[rr] += hs[half * 4 + rr][c] * wa + ms[half * 4 + rr][c] * wb;
    }
#pragma unroll
    for (int rr = 0; rr < 4; rr++) ss[half * 4 + rr][k] = silu(acc[rr]);
    __syncthreads();
    float bb2 = b2n[k];
    float a2[4];
#pragma unroll
    for (int rr = 0; rr < 4; rr++) a2[rr] = bb2;
#pragma unroll 4
    for (int c = 0; c < Hc; c++) {
        float wv = w2n[c * Hc + k];
#pragma unroll
        for (int rr = 0; rr < 4; rr++) a2[rr] += ss[half * 4 + rr][c] * wv;
    }
    float hnew[4];
#pragma unroll
    for (int rr = 0; rr < 4; rr++) {
        hnew[rr] = hs[half * 4 + rr][k] + a2[rr];
        hout[(r0 + half * 4 + rr) * Hc + k] = hnew[rr];
    }
    if (do_hij) {
        __syncthreads();   // everyone done reading old hs
#pragma unroll
        for (int rr = 0; rr < 4; rr++) hs[half * 4 + rr][k] = hnew[rr];
        __syncthreads();
        float bias1 = b1e[k] + w1e[(2 * Hc + 1) * Hc + k];
        float a1[4], b1v[4];
#pragma unroll
        for (int rr = 0; rr < 4; rr++) { a1[rr] = bias1; b1v[rr] = 0.f; }
#pragma unroll 4
        for (int c = 0; c < Hc; c++) {
            float wa = w1e[c * Hc + k];
            float wb = w1e[(Hc + c) * Hc + k];
#pragma unroll
            for (int rr = 0; rr < 4; rr++) {
                a1[rr] += hs[half * 4 + rr][c] * wa;
                b1v[rr] += hs[half * 4 + rr][c] * wb;
            }
        }
#pragma unroll
        for (int rr = 0; rr < 4; rr++) {
            hi[(r0 + half * 4 + rr) * Hc + k] = a1[rr];
            hj[(r0 + half * 4 + rr) * Hc + k] = b1v[rr];
        }
    }
}

extern "C" void kernel_launch(void* const* d_in, const int* in_sizes, int n_in,
                              void* d_out, int out_size, void* d_ws, size_t ws_size,
                              hipStream_t stream) {
    const float* coords     = (const float*)d_in[0];
    const float* contacts   = (const float*)d_in[1];
    const float* node_feats = (const float*)d_in[2];
    const float* in_w       = (const float*)d_in[3];
    const float* in_b       = (const float*)d_in[4];
    const float* e_w1       = (const float*)d_in[5];   // 3 x 258 x 128
    const float* e_b1       = (const float*)d_in[6];
    const float* e_w2       = (const float*)d_in[7];   // 3 x 128 x 128
    const float* e_b2       = (const float*)d_in[8];
    const float* n_w1       = (const float*)d_in[9];   // 3 x 256 x 128
    const float* n_b1       = (const float*)d_in[10];
    const float* n_w2       = (const float*)d_in[11];  // 3 x 128 x 128
    const float* n_b2       = (const float*)d_in[12];

    float* ws = (float*)d_ws;
    float* h  = ws;                 // 131072 floats
    float* hi = ws + 131072;
    float* hj = ws + 262144;
    float* m  = ws + 393216;
    unsigned short* elist = (unsigned short*)(ws + 524288);  // ROWS*Lc u16 = 1 MiB
    int* ecnt = (int*)(ws + 524288 + 262144);                // after elist

    build_edges<<<ROWS, 64, 0, stream>>>(contacts, elist, ecnt);
    input_proj_hij<<<ROWS / 8, 256, 0, stream>>>(
        node_feats, in_w, in_b, e_w1, e_b1, h, hi, hj);

    for (int l = 0; l < 3; l++) {
        const float* w1  = e_w1 + (size_t)l * 258 * Hc;
        const float* w2e = e_w2 + (size_t)l * Hc * Hc;
        const float* w1n = n_w1 + (size_t)l * 256 * Hc;
        const float* w2n = n_w2 + (size_t)l * Hc * Hc;
        edge_kernel<<<ROWS, 256, 0, stream>>>(hi, hj, coords, elist, ecnt,
                                              w1 + 2 * Hc * Hc, w2e,
                                              e_b2 + l * Hc, m);
        int do_hij = (l < 2);
        const float* w1e_next = e_w1 + (size_t)(l + 1 < 3 ? l + 1 : 0) * 258 * Hc;
        const float* b1e_next = e_b1 + (size_t)(l + 1 < 3 ? l + 1 : 0) * Hc;
        float* hout = (l == 2) ? (float*)d_out : h;
        node_hij_kernel<<<ROWS / 8, 256, 0, stream>>>(
            h, m, w1n, n_b1 + l * Hc, w2n, n_b2 + l * Hc,
            hout, do_hij, w1e_next, b1e_next, hi, hj);
    }
}

// Round 5
// 229.244 us; speedup vs baseline: 1.5329x; 1.4828x over previous
//
#include <hip/hip_runtime.h>
#include <hip/hip_bf16.h>

// SE3StructEncoder: sparse edge-MLP graph network. B=2, L=512, H=128, 3 layers.
// Round 5: edge GEMM -> bf16 MFMA (16x16x32), w2 transposed to bf16 and held in
// registers; coalesced 64B hj gather; shfl colsum; node/input kernels 2 rows/block.

#define Hc 128
#define Lc 512
#define ROWS 1024     // B*L

typedef __bf16 bf16x8 __attribute__((ext_vector_type(8)));
typedef float  f32x4  __attribute__((ext_vector_type(4)));

__device__ __forceinline__ float silu(float x) {
    return x / (1.f + __expf(-x));
}

// ---------------- edge-list build: one wave per (b,i) row ----------------
__global__ __launch_bounds__(64) void build_edges(
    const float* __restrict__ contacts,
    unsigned short* __restrict__ elist, int* __restrict__ ecnt) {
    int r = blockIdx.x;
    int lane = threadIdx.x;
    const float* row = contacts + (size_t)r * Lc;
    int cnt = 0;
    for (int base = 0; base < Lc; base += 64) {
        float v = row[base + lane];
        unsigned long long mask = __ballot(v > 0.f);
        if (v > 0.f) {
            int pos = cnt + __popcll(mask & ((1ull << lane) - 1ull));
            elist[r * Lc + pos] = (unsigned short)(base + lane);
        }
        cnt += __popcll(mask);
    }
    if (lane == 0) ecnt[r] = cnt;
}

// ---------- w2 -> bf16 transposed [layer][col][k] (one-time per launch) ----------
__global__ __launch_bounds__(128) void prep_w2t(
    const float* __restrict__ e_w2, __bf16* __restrict__ w2t) {
    int lc = blockIdx.x;            // layer*128 + col
    int l  = lc >> 7, col = lc & 127;
    int k  = threadIdx.x;
    w2t[(size_t)lc * Hc + k] =
        (__bf16)e_w2[(size_t)l * Hc * Hc + (size_t)k * Hc + col];
}

// ------- input proj + layer-0 hi/hj: 2 rows per block, 256 threads -------
__global__ __launch_bounds__(256) void input_proj_hij(
    const float* __restrict__ nf, const float* __restrict__ in_w,
    const float* __restrict__ in_b,
    const float* __restrict__ w1, const float* __restrict__ b1,
    float* __restrict__ h, float* __restrict__ hi, float* __restrict__ hj) {
    int r0 = blockIdx.x * 2;
    int t = threadIdx.x;
    int k = t & 127, row = t >> 7;
    __shared__ float nfs[2][32];
    __shared__ float hs[2][Hc];
    if (t < 64) nfs[t >> 5][t & 31] = nf[r0 * 32 + t];
    __syncthreads();
    float acc = in_b[k];
#pragma unroll 4
    for (int c = 0; c < 32; c++) acc += nfs[row][c] * in_w[c * Hc + k];
    h[(size_t)(r0 + row) * Hc + k] = acc;
    hs[row][k] = acc;
    __syncthreads();
    float a1 = b1[k] + w1[(2 * Hc + 1) * Hc + k];   // contact fold
    float a2 = 0.f;
#pragma unroll 4
    for (int c = 0; c < Hc; c++) {
        float hv = hs[row][c];
        a1 += hv * w1[c * Hc + k];
        a2 += hv * w1[(Hc + c) * Hc + k];
    }
    hi[(size_t)(r0 + row) * Hc + k] = a1;
    hj[(size_t)(r0 + row) * Hc + k] = a2;
}

// ---------------- edge kernel: per (b,i) row, sparse edges, MFMA ----------------
// m_i = sum_{j in edges(i)} silu( silu(pre_ij) @ w2 + b2 )
// pre_ij = hi'[i] + hj[j] + dist(i,j)*w1d   (b1 + contact*w1c folded into hi')
// S (32 edges x 128 c) staged as bf16 in LDS, 16B-block XOR-swizzled by (row&7).
// B (w2t bf16, [col][k]) lives in 8 register fragments per wave for the whole kernel.
__global__ __launch_bounds__(256) void edge_kernel(
    const float* __restrict__ hi, const float* __restrict__ hj,
    const float* __restrict__ coords,
    const unsigned short* __restrict__ elist, const int* __restrict__ ecnt,
    const float* __restrict__ w1d, const __bf16* __restrict__ w2t,
    const float* __restrict__ b2, float* __restrict__ m_out) {
    int r = blockIdx.x;
    int b = r >> 9;
    int i = r & (Lc - 1);
    int t = threadIdx.x;
    int l = t & 63, w = t >> 6;          // lane, wave (wave w owns cols w*32..+31)

    __shared__ __bf16 S[32 * Hc];        // swizzled [edge][c]
    __shared__ float dL[Lc];
    __shared__ unsigned short jLs[Lc];

    int cnt = ecnt[r];

    float cx = coords[(b * Lc + i) * 3 + 0];
    float cy = coords[(b * Lc + i) * 3 + 1];
    float cz = coords[(b * Lc + i) * 3 + 2];
    for (int e = t; e < cnt; e += 256) {
        int j = elist[r * Lc + e];
        float dx = cx - coords[(b * Lc + j) * 3 + 0];
        float dy = cy - coords[(b * Lc + j) * 3 + 1];
        float dz = cz - coords[(b * Lc + j) * 3 + 2];
        dL[e] = sqrtf(dx * dx + dy * dy + dz * dz);
        jLs[e] = (unsigned short)j;
    }

    // fill-role constants: thread owns (edge e_f, 16-col slice c0)
    int e_f = t >> 3;                    // 0..31
    int cg  = t & 7;
    int c0  = cg * 16;
    float4 hi4[4], wd4[4];
#pragma unroll
    for (int q = 0; q < 4; q++) {
        hi4[q] = *(const float4*)&hi[(size_t)r * Hc + c0 + q * 4];
        wd4[q] = *(const float4*)&w1d[c0 + q * 4];
    }

    // B fragments: B[k][col], lane holds col=(l&15) of its N-tile, k-slice (l>>4)*8
    bf16x8 bf[2][4];
#pragma unroll
    for (int nt = 0; nt < 2; nt++)
#pragma unroll
        for (int kk = 0; kk < 4; kk++)
            bf[nt][kk] = *(const bf16x8*)&w2t[
                (size_t)(w * 32 + nt * 16 + (l & 15)) * Hc + kk * 32 + (l >> 4) * 8];

    float b2v[2] = { b2[w * 32 + (l & 15)], b2[w * 32 + 16 + (l & 15)] };
    float msum[2] = { 0.f, 0.f };

    __syncthreads();

    int row0 = l & 15, g = l >> 4, swz = l & 7;
    for (int base = 0; base < cnt; base += 32) {
        // ---- fill S (bf16, swizzled) ----
        bf16x8 o0, o1;
        if (base + e_f < cnt) {
            int j = jLs[base + e_f];
            float d = dL[base + e_f];
            const float* hjrow = hj + ((size_t)(b * Lc + j)) * Hc + c0;
            float v[16];
#pragma unroll
            for (int q = 0; q < 4; q++) {
                float4 hjv = *(const float4*)&hjrow[q * 4];
                v[q * 4 + 0] = silu(hi4[q].x + hjv.x + d * wd4[q].x);
                v[q * 4 + 1] = silu(hi4[q].y + hjv.y + d * wd4[q].y);
                v[q * 4 + 2] = silu(hi4[q].z + hjv.z + d * wd4[q].z);
                v[q * 4 + 3] = silu(hi4[q].w + hjv.w + d * wd4[q].w);
            }
#pragma unroll
            for (int u = 0; u < 8; u++) {
                o0[u] = (__bf16)v[u];
                o1[u] = (__bf16)v[8 + u];
            }
        } else {
#pragma unroll
            for (int u = 0; u < 8; u++) { o0[u] = (__bf16)0.f; o1[u] = (__bf16)0.f; }
        }
        int sw = e_f & 7;
        *(bf16x8*)&S[e_f * Hc + ((cg * 2) ^ sw) * 8]     = o0;
        *(bf16x8*)&S[e_f * Hc + ((cg * 2 + 1) ^ sw) * 8] = o1;
        __syncthreads();

        // ---- MFMA: D[edge][col] = S @ w2 ----
        f32x4 acc[2][2] = {};
#pragma unroll
        for (int kk = 0; kk < 4; kk++) {
            bf16x8 a0 = *(const bf16x8*)&S[row0 * Hc + (((kk * 4 + g) ^ swz)) * 8];
            bf16x8 a1 = *(const bf16x8*)&S[(16 + row0) * Hc + (((kk * 4 + g) ^ swz)) * 8];
            acc[0][0] = __builtin_amdgcn_mfma_f32_16x16x32_bf16(a0, bf[0][kk], acc[0][0], 0, 0, 0);
            acc[0][1] = __builtin_amdgcn_mfma_f32_16x16x32_bf16(a0, bf[1][kk], acc[0][1], 0, 0, 0);
            acc[1][0] = __builtin_amdgcn_mfma_f32_16x16x32_bf16(a1, bf[0][kk], acc[1][0], 0, 0, 0);
            acc[1][1] = __builtin_amdgcn_mfma_f32_16x16x32_bf16(a1, bf[1][kk], acc[1][1], 0, 0, 0);
        }

        // ---- second silu + predicated colsum into registers ----
#pragma unroll
        for (int mt = 0; mt < 2; mt++)
#pragma unroll
            for (int nt = 0; nt < 2; nt++)
#pragma unroll
                for (int jj = 0; jj < 4; jj++) {
                    int er = mt * 16 + g * 4 + jj;   // D row = 4*(lane>>4)+reg (+16*mt)
                    if (base + er < cnt)
                        msum[nt] += silu(acc[mt][nt][jj] + b2v[nt]);
                }
        __syncthreads();   // protect S before next fill
    }

    // cross-lane colsum: lanes l, l^16, l^32 share col (l&15)
    float v0 = msum[0]; v0 += __shfl_xor(v0, 16); v0 += __shfl_xor(v0, 32);
    float v1 = msum[1]; v1 += __shfl_xor(v1, 16); v1 += __shfl_xor(v1, 32);
    if (l < 16) {
        m_out[(size_t)r * Hc + w * 32 + l]      = v0;
        m_out[(size_t)r * Hc + w * 32 + 16 + l] = v1;
    }
}

// ------- node update (+ next layer hi/hj): 2 rows per block, 256 threads -------
// h' = h + silu(h@w1n[:H] + m@w1n[H:] + b1n)@w2n + b2n
// if do_hij: hi = h'@w1e[:H] + b1e + w1e[257];  hj = h'@w1e[H:2H]
__global__ __launch_bounds__(256) void node_hij_kernel(
    const float* __restrict__ h, const float* __restrict__ m,
    const float* __restrict__ w1n, const float* __restrict__ b1n,
    const float* __restrict__ w2n, const float* __restrict__ b2n,
    float* __restrict__ hout, int do_hij,
    const float* __restrict__ w1e, const float* __restrict__ b1e,
    float* __restrict__ hi, float* __restrict__ hj) {
    int r0 = blockIdx.x * 2;
    int t = threadIdx.x;
    int k = t & 127, row = t >> 7;
    __shared__ float hs[2][Hc], ms[2][Hc], ss[2][Hc];
    hs[row][k] = h[(size_t)(r0 + row) * Hc + k];
    ms[row][k] = m[(size_t)(r0 + row) * Hc + k];
    __syncthreads();
    float acc = b1n[k];
#pragma unroll 4
    for (int c = 0; c < Hc; c++)
        acc += hs[row][c] * w1n[c * Hc + k] + ms[row][c] * w1n[(Hc + c) * Hc + k];
    ss[row][k] = silu(acc);
    __syncthreads();
    float a2 = b2n[k];
#pragma unroll 4
    for (int c = 0; c < Hc; c++) a2 += ss[row][c] * w2n[c * Hc + k];
    float hnew = hs[row][k] + a2;
    hout[(size_t)(r0 + row) * Hc + k] = hnew;
    if (do_hij) {
        __syncthreads();   // everyone done reading old hs
        hs[row][k] = hnew;
        __syncthreads();
        float a1 = b1e[k] + w1e[(2 * Hc + 1) * Hc + k];
        float aj = 0.f;
#pragma unroll 4
        for (int c = 0; c < Hc; c++) {
            float hv = hs[row][c];
            a1 += hv * w1e[c * Hc + k];
            aj += hv * w1e[(Hc + c) * Hc + k];
        }
        hi[(size_t)(r0 + row) * Hc + k] = a1;
        hj[(size_t)(r0 + row) * Hc + k] = aj;
    }
}

extern "C" void kernel_launch(void* const* d_in, const int* in_sizes, int n_in,
                              void* d_out, int out_size, void* d_ws, size_t ws_size,
                              hipStream_t stream) {
    const float* coords     = (const float*)d_in[0];
    const float* contacts   = (const float*)d_in[1];
    const float* node_feats = (const float*)d_in[2];
    const float* in_w       = (const float*)d_in[3];
    const float* in_b       = (const float*)d_in[4];
    const float* e_w1       = (const float*)d_in[5];   // 3 x 258 x 128
    const float* e_b1       = (const float*)d_in[6];
    const float* e_w2       = (const float*)d_in[7];   // 3 x 128 x 128
    const float* e_b2       = (const float*)d_in[8];
    const float* n_w1       = (const float*)d_in[9];   // 3 x 256 x 128
    const float* n_b1       = (const float*)d_in[10];
    const float* n_w2       = (const float*)d_in[11];  // 3 x 128 x 128
    const float* n_b2       = (const float*)d_in[12];

    float* ws = (float*)d_ws;
    float* h  = ws;                                    // 131072 floats
    float* hi = ws + 131072;
    float* hj = ws + 262144;
    float* m  = ws + 393216;
    unsigned short* elist = (unsigned short*)(ws + 524288);   // 1 MiB = 262144 floats
    int*   ecnt = (int*)(ws + 786432);                        // 1024 ints
    __bf16* w2t = (__bf16*)(ws + 787456);                     // 3*128*128 bf16 = 24576 floats

    prep_w2t<<<3 * Hc, 128, 0, stream>>>(e_w2, w2t);
    build_edges<<<ROWS, 64, 0, stream>>>(contacts, elist, ecnt);
    input_proj_hij<<<ROWS / 2, 256, 0, stream>>>(
        node_feats, in_w, in_b, e_w1, e_b1, h, hi, hj);

    for (int l = 0; l < 3; l++) {
        const float* w1  = e_w1 + (size_t)l * 258 * Hc;
        const float* w1n = n_w1 + (size_t)l * 256 * Hc;
        const float* w2n = n_w2 + (size_t)l * Hc * Hc;
        edge_kernel<<<ROWS, 256, 0, stream>>>(hi, hj, coords, elist, ecnt,
                                              w1 + 2 * Hc * Hc,
                                              w2t + (size_t)l * Hc * Hc,
                                              e_b2 + l * Hc, m);
        int do_hij = (l < 2);
        const float* w1e_next = e_w1 + (size_t)(l + 1 < 3 ? l + 1 : 0) * 258 * Hc;
        const float* b1e_next = e_b1 + (size_t)(l + 1 < 3 ? l + 1 : 0) * Hc;
        float* hout = (l == 2) ? (float*)d_out : h;
        node_hij_kernel<<<ROWS / 2, 256, 0, stream>>>(
            h, m, w1n, n_b1 + l * Hc, w2n, n_b2 + l * Hc,
            hout, do_hij, w1e_next, b1e_next, hi, hj);
    }
}